// Round 9
// baseline (159.947 us; speedup 1.0000x reference)
//
#include <hip/hip_runtime.h>
#include <hip/hip_bf16.h>

#define NN 256
#define FI 128
#define FO 64
#define LOG2E 1.4426950408889634f

typedef short s16x8 __attribute__((ext_vector_type(8)));
typedef float f32x4 __attribute__((ext_vector_type(4)));

__device__ __forceinline__ unsigned f2bf1(float x) {
  union { float f; unsigned u; } v; v.f = x;
  unsigned r = v.u + 0x7FFFu + ((v.u >> 16) & 1u);
  return r >> 16;
}
__device__ __forceinline__ unsigned pack2(float a, float b) {
  return f2bf1(a) | (f2bf1(b) << 16);
}
// one-instruction bf16x2 pack (truncation) via v_perm_b32 — alpha only
__device__ __forceinline__ unsigned pktrunc(float lo, float hi) {
  union { float f; unsigned u; } a, b; a.f = hi; b.f = lo;
  return __builtin_amdgcn_perm(a.u, b.u, 0x07060302u);
}
__device__ __forceinline__ float fexp2(float x) {
#if __has_builtin(__builtin_amdgcn_exp2f)
  return __builtin_amdgcn_exp2f(x);
#else
  return exp2f(x);
#endif
}

// async global->LDS, 16B per lane, zero VGPR round-trip (vmcnt-tracked;
// __syncthreads drains it). LDS dest = wave-uniform base + lane*16 (m104).
__device__ __forceinline__ void gload_lds16(const void* g, void* l) {
#if __has_builtin(__builtin_amdgcn_global_load_lds)
  __builtin_amdgcn_global_load_lds(
      (const __attribute__((address_space(1))) unsigned*)g,
      (__attribute__((address_space(3))) unsigned*)l, 16, 0, 0);
#else
  *(uint4*)l = *(const uint4*)g;   // fallback (sync copy)
#endif
}

// ---------------- Kernel 0: adj -> 256-bit row bitmasks (8 KB total).
// Replaces per-lane divergent adj float4 loads in attn's softmax (16 loads x
// 16-segment divergence per lane -- the round 5-8 latency killer) with 2
// uint4 loads per row from an L1-resident table.
__global__ __launch_bounds__(256) void gat_k0(const float* __restrict__ adj,
                                              unsigned* __restrict__ msk) {
  const int row = blockIdx.x;
  const int wv = threadIdx.x >> 6, lane = threadIdx.x & 63;
  float v = adj[row * NN + wv * 64 + lane];
  unsigned long long b = __ballot(v > 0.f);
  if (lane == 0) {
    msk[row * 8 + wv * 2]     = (unsigned)b;
    msk[row * 8 + wv * 2 + 1] = (unsigned)(b >> 32);
  }
}

// ---------------- Kernel A: GEMM-1. One barrier, 17 KB LDS (W^T staging).
// 256 threads = 4 waves; each wave owns ONE 16-row subtile of Wh.
// grid = 512 graphs * 4 quarters. Writes:
//   whG  : bf16 Wh in GEMM-2 fragment-chunk layout (32 KB/graph),
//          q-slot swizzled by (m&3)^((m>>2)&3) so kernel B's LDS reads are 2-way
//   wh1G/wh2G : fp32, pre-scaled by LOG2E
__global__ __launch_bounds__(256, 4)
void gat_wh(const float* __restrict__ h, const float* __restrict__ W,
            const float* __restrict__ a,
            unsigned short* __restrict__ whG,
            float* __restrict__ wh1G, float* __restrict__ wh2G)
{
  const int bid  = blockIdx.x;
  const int g    = bid >> 2;          // graph (b*t)
  const int qt   = bid & 3;           // quarter: rows 64*qt..+63
  const int tid  = threadIdx.x;
  const int lane = tid & 63;
  const int w2   = tid >> 6;          // wave 0..3
  const int m    = lane & 15;
  const int q    = lane >> 4;
  const int R    = 64 * qt + 16 * w2; // wave's 16-row base (16-aligned)

  __shared__ __align__(16) unsigned short sWT[64 * 136]; // bf16 W^T [o][k], padded

  const float* __restrict__ hB = h + (size_t)g * NN * FI;

  // 16 rows of h: lane (m,q) -> row R+m, cols kt*32 + q*8 (+0,+4). Issued up front.
  float4 x[4][2];
  #pragma unroll
  for (int kt = 0; kt < 4; ++kt) {
    const float* p = hB + (size_t)(R + m) * FI + kt * 32 + q * 8;
    x[kt][0] = *(const float4*)p;
    x[kt][1] = *(const float4*)(p + 4);
  }

  // Stage W (fp32 [k][o], 32 KB, L2-hot) -> sWT bf16 [o][k].
  // k-paired: read rows k,k+1 same o-quad, pack along k -> 16 ds_write_b32
  // per thread. 4 iters x 256 thr x (2k x 4o) = 8192.
  #pragma unroll
  for (int it = 0; it < 4; ++it) {
    int idx = it * 256 + tid;          // 0..1023
    int k   = (idx >> 4) << 1;         // even k: 0,2,..,126
    int o   = (idx & 15) << 2;         // 0,4,..,60
    float4 wa = *(const float4*)&W[k * FO + o];
    float4 wb = *(const float4*)&W[(k + 1) * FO + o];
    *(unsigned*)&sWT[(o + 0) * 136 + k] = pack2(wa.x, wb.x);
    *(unsigned*)&sWT[(o + 1) * 136 + k] = pack2(wa.y, wb.y);
    *(unsigned*)&sWT[(o + 2) * 136 + k] = pack2(wa.z, wb.z);
    *(unsigned*)&sWT[(o + 3) * 136 + k] = pack2(wa.w, wb.w);
  }

  // a-vector values (512 B, L1-broadcast)
  float a1v[4], a2v[4];
  #pragma unroll
  for (int nt = 0; nt < 4; ++nt) {
    a1v[nt] = a[16 * nt + m];
    a2v[nt] = a[FO + 16 * nt + m];
  }

  s16x8 af[4];
  #pragma unroll
  for (int kt = 0; kt < 4; ++kt) {
    union { unsigned u[4]; s16x8 v; } pk;
    pk.u[0] = pack2(x[kt][0].x, x[kt][0].y);
    pk.u[1] = pack2(x[kt][0].z, x[kt][0].w);
    pk.u[2] = pack2(x[kt][1].x, x[kt][1].y);
    pk.u[3] = pack2(x[kt][1].z, x[kt][1].w);
    af[kt] = pk.v;
  }

  __syncthreads();   // sWT ready

  f32x4 acc[4];
  #pragma unroll
  for (int nt = 0; nt < 4; ++nt) acc[nt] = (f32x4){0.f, 0.f, 0.f, 0.f};
  #pragma unroll
  for (int kt = 0; kt < 4; ++kt)
    #pragma unroll
    for (int nt = 0; nt < 4; ++nt) {
      s16x8 bf = *(const s16x8*)&sWT[(16 * nt + m) * 136 + kt * 32 + q * 8];
      acc[nt] = __builtin_amdgcn_mfma_f32_16x16x32_bf16(af[kt], bf, acc[nt], 0, 0, 0);
    }

  // wh1/wh2 epilogue (acc[nt][r] = Wh[R+4q+r][16nt+m]); store x log2e
  {
    float p1[4] = {0.f,0.f,0.f,0.f}, p2[4] = {0.f,0.f,0.f,0.f};
    #pragma unroll
    for (int nt = 0; nt < 4; ++nt) {
      #pragma unroll
      for (int r = 0; r < 4; ++r) { p1[r] += acc[nt][r] * a1v[nt]; p2[r] += acc[nt][r] * a2v[nt]; }
    }
    #pragma unroll
    for (int off = 1; off < 16; off <<= 1)
      #pragma unroll
      for (int r = 0; r < 4; ++r) {
        p1[r] += __shfl_xor(p1[r], off);
        p2[r] += __shfl_xor(p2[r], off);
      }
    if (m == 0) {
      *(float4*)&wh1G[g * NN + R + 4 * q] =
          make_float4(p1[0]*LOG2E, p1[1]*LOG2E, p1[2]*LOG2E, p1[3]*LOG2E);
      *(float4*)&wh2G[g * NN + R + 4 * q] =
          make_float4(p2[0]*LOG2E, p2[1]*LOG2E, p2[2]*LOG2E, p2[3]*LOG2E);
    }
  }

  // Wh -> global frag-chunk layout, q-slot PRE-SWIZZLED for kernel B's LDS
  // bank pattern (rule #21: swizzled source + linear LDS copy + swizzled read).
  // chunk = ((Wv*4+nt)*16+m)*4 + (qB ^ (m&3) ^ ((m>>2)&3)), 16B chunks.
  {
    const int Wv  = R >> 5;          // 0..7 (matches GEMM-2's kt)
    const int S   = (R >> 4) & 1;
    const int qB  = (2 * S + (q >> 1)) & 3;
    const int swz = (m & 3) ^ ((m >> 2) & 3);
    unsigned short* whP = whG + (size_t)g * (NN * FO);
    #pragma unroll
    for (int nt = 0; nt < 4; ++nt) {
      int chunk = ((Wv * 4 + nt) * 16 + m) * 4 + (qB ^ swz);
      uint2 wrv;
      wrv.x = pack2(acc[nt][0], acc[nt][1]);
      wrv.y = pack2(acc[nt][2], acc[nt][3]);
      *(uint2*)((char*)whP + chunk * 16 + (q & 1) * 8) = wrv;
    }
  }
}

// ---------------- Kernel B: softmax + GEMM-2 + elu.
// ONE block per graph: 512 threads = 8 waves; wave w2 owns rows 32*w2..+31 in
// TWO rounds of 16. grid = 512. The graph's 32 KB whG is staged ONCE (async
// global_load_lds, zero regs held; the round-0 softmax hides the drain, one
// __syncthreads before the first LDS read). Masking uses 256-bit row bitmasks
// (8 KB, L1-resident) -- kills the divergent adj float4 loads that kept
// rounds 5-8 latency-bound (~30 us vs ~12 us floor, insensitive to staging/
// occupancy changes). waves_per_eu(4,8): VGPR cap 128 -> 2 resident blocks/CU
// by both VGPR (4 waves/SIMD) and LDS (64 of 160 KB).
__global__ __launch_bounds__(512)
__attribute__((amdgpu_waves_per_eu(4, 8)))
void gat_attn(const unsigned short* __restrict__ whG,
              const float* __restrict__ wh1G, const float* __restrict__ wh2G,
              const unsigned* __restrict__ msk, float* __restrict__ out)
{
  const int g    = blockIdx.x;
  const int tid  = threadIdx.x;
  const int lane = tid & 63;
  const int w2   = tid >> 6;                // wave 0..7
  const int m    = lane & 15;
  const int q    = lane >> 4;

  __shared__ __align__(16) unsigned short sWh[NN * FO]; // 32 KB staged Wh

  const unsigned short* __restrict__ whP = whG + (size_t)g * (NN * FO);
  const float* __restrict__ wh2B = wh2G + g * NN;
  float* outB = out + (size_t)g * NN * FO;

  // ---- stage: async copy of the graph's 32 KB whG into LDS (linear copy;
  // swizzle pre-baked in whG's global layout). 4 x 16B per thread, coalesced,
  // zero registers held; drained by the __syncthreads below.
  #pragma unroll
  for (int i = 0; i < 4; ++i) {
    int c = i * 512 + tid;
    gload_lds16(whP + (size_t)c * 8, &sWh[(size_t)c * 8]);
  }

  const int swz = (m & 3) ^ ((m >> 2) & 3);

  #pragma unroll
  for (int t = 0; t < 2; ++t) {
    const int row = 32 * w2 + 16 * t + m;   // this lane's attention row

    // row bitmask: 2 x uint4 (32B) per row, L1-hot table
    const uint4 mka = *(const uint4*)&msk[row * 8];
    const uint4 mkb = *(const uint4*)&msk[row * 8 + 4];
    const unsigned mkw[8] = {mka.x, mka.y, mka.z, mka.w, mkb.x, mkb.y, mkb.z, mkb.w};
    const float w1 = wh1G[g * NN + row];    // pre-scaled by log2e

    // ---- softmax: pure ALU + wave-uniform wh2 loads (1 KB/graph, L1-hot)
    s16x8 A[8];                             // alpha, B-fragment layout
    float sum = 0.f;
    #pragma unroll
    for (int kt = 0; kt < 8; ++kt) {
      int j0 = kt * 32 + q * 8;
      float4 w20 = *(const float4*)&wh2B[j0];
      float4 w21 = *(const float4*)&wh2B[j0 + 4];
      unsigned wq = mkw[kt] >> (q * 8);
      float p[8];
      const float w2e[8] = {w20.x, w20.y, w20.z, w20.w, w21.x, w21.y, w21.z, w21.w};
      #pragma unroll
      for (int e = 0; e < 8; ++e) {
        float l = w1 + w2e[e];
        l = fmaxf(l, 0.01f * l);                 // leaky-relu (log2e pre-folded)
        union { float f; int i; } u_; u_.f = fexp2(l);
        u_.i &= ((int)(wq << (31 - e))) >> 31;   // adj bit -> 0 / all-ones
        p[e] = u_.f;
        sum += u_.f;
      }
      union { unsigned u[4]; s16x8 v; } pk;
      pk.u[0] = pktrunc(p[0], p[1]);
      pk.u[1] = pktrunc(p[2], p[3]);
      pk.u[2] = pktrunc(p[4], p[5]);
      pk.u[3] = pktrunc(p[6], p[7]);
      A[kt] = pk.v;
    }
    sum += __shfl_xor(sum, 16);
    sum += __shfl_xor(sum, 32);
    const float inv = __builtin_amdgcn_rcpf(sum);

    if (t == 0) __syncthreads();   // drains vmcnt: staging landed; sWh ready

    // ---- GEMM-2 swapped: D = Wh^T(A-op) @ alpha^T(B-op), fragments from LDS.
    // Read swizzle matches gat_wh's write swizzle -> contiguous 1 KB per wave
    // instruction (conflict-free).
    f32x4 acc[4];
    #pragma unroll
    for (int ot = 0; ot < 4; ++ot) acc[ot] = (f32x4){0.f, 0.f, 0.f, 0.f};
    #pragma unroll
    for (int kt = 0; kt < 8; ++kt) {
      #pragma unroll
      for (int ot = 0; ot < 4; ++ot) {
        int chunk = ((kt * 4 + ot) * 16 + m) * 4 + (q ^ swz);
        s16x8 whf = *(const s16x8*)&sWh[chunk * 8];
        acc[ot] = __builtin_amdgcn_mfma_f32_16x16x32_bf16(whf, A[kt], acc[ot], 0, 0, 0);
      }
    }

    // epilogue: lane(m,q) holds out[row][16ot+4q .. +3]
    #pragma unroll
    for (int ot = 0; ot < 4; ++ot) {
      float4 v4;
      float* vp = (float*)&v4;
      #pragma unroll
      for (int r = 0; r < 4; ++r) {
        float v = acc[ot][r] * inv;
        float ev = fexp2(v * LOG2E) - 1.f;
        vp[r] = v > 0.f ? v : ev;
      }
      *(float4*)&outB[row * FO + 16 * ot + 4 * q] = v4;
    }
  }
}

extern "C" void kernel_launch(void* const* d_in, const int* in_sizes, int n_in,
                              void* d_out, int out_size, void* d_ws, size_t ws_size,
                              hipStream_t stream) {
  const float* h   = (const float*)d_in[0];
  const float* W   = (const float*)d_in[1];
  const float* a   = (const float*)d_in[2];
  const float* adj = (const float*)d_in[3];
  float* out = (float*)d_out;

  // workspace layout (all 16B-aligned):
  //   msk  : 8 KiB    (256-bit adjacency bitmask per row)
  //   wh1G : 512 KiB  (fp32, pre-scaled by log2e)
  //   wh2G : 512 KiB
  //   whG  : 16 MiB   (bf16 Wh, frag-chunk layout, 32 KB/graph)
  char* ws = (char*)d_ws;
  unsigned*        msk  = (unsigned*)(ws);
  float*           wh1G = (float*)(ws + 8192);
  float*           wh2G = (float*)(ws + 8192 + 524288);
  unsigned short*  whG  = (unsigned short*)(ws + 8192 + 2 * 524288);

  gat_k0  <<<dim3(256),  dim3(256), 0, stream>>>(adj, msk);
  gat_wh  <<<dim3(2048), dim3(256), 0, stream>>>(h, W, a, whG, wh1G, wh2G);
  gat_attn<<<dim3(512),  dim3(512), 0, stream>>>(whG, wh1G, wh2G, msk, out);
}

// Round 10
// 130.012 us; speedup vs baseline: 1.2302x; 1.2302x over previous
//
#include <hip/hip_runtime.h>
#include <hip/hip_bf16.h>

#define NN 256
#define FI 128
#define FO 64
#define LOG2E 1.4426950408889634f

typedef short s16x8 __attribute__((ext_vector_type(8)));
typedef float f32x4 __attribute__((ext_vector_type(4)));

__device__ __forceinline__ unsigned f2bf1(float x) {
  union { float f; unsigned u; } v; v.f = x;
  unsigned r = v.u + 0x7FFFu + ((v.u >> 16) & 1u);
  return r >> 16;
}
__device__ __forceinline__ unsigned pack2(float a, float b) {
  return f2bf1(a) | (f2bf1(b) << 16);
}
// one-instruction bf16x2 pack (truncation) via v_perm_b32 — alpha only
__device__ __forceinline__ unsigned pktrunc(float lo, float hi) {
  union { float f; unsigned u; } a, b; a.f = hi; b.f = lo;
  return __builtin_amdgcn_perm(a.u, b.u, 0x07060302u);
}
__device__ __forceinline__ float fexp2(float x) {
#if __has_builtin(__builtin_amdgcn_exp2f)
  return __builtin_amdgcn_exp2f(x);
#else
  return exp2f(x);
#endif
}

// async global->LDS, 16B per lane, zero VGPR round-trip (vmcnt-tracked;
// __syncthreads drains it). LDS dest = wave-uniform base + lane*16 (m104).
__device__ __forceinline__ void gload_lds16(const void* g, void* l) {
#if __has_builtin(__builtin_amdgcn_global_load_lds)
  __builtin_amdgcn_global_load_lds(
      (const __attribute__((address_space(1))) unsigned*)g,
      (__attribute__((address_space(3))) unsigned*)l, 16, 0, 0);
#else
  *(uint4*)l = *(const uint4*)g;   // fallback (sync copy)
#endif
}

// ---------------- Kernel 0: adj -> 256-bit row bitmasks (8 KB total).
// Replaces per-lane divergent adj float4 loads in attn's softmax (16 loads x
// 16-segment divergence per lane) with 2 uint4 loads per row, L1-resident.
__global__ __launch_bounds__(256) void gat_k0(const float* __restrict__ adj,
                                              unsigned* __restrict__ msk) {
  const int row = blockIdx.x;
  const int wv = threadIdx.x >> 6, lane = threadIdx.x & 63;
  float v = adj[row * NN + wv * 64 + lane];
  unsigned long long b = __ballot(v > 0.f);
  if (lane == 0) {
    msk[row * 8 + wv * 2]     = (unsigned)b;
    msk[row * 8 + wv * 2 + 1] = (unsigned)(b >> 32);
  }
}

// ---------------- Kernel A: GEMM-1. One barrier, 17 KB LDS (W^T staging).
// 256 threads = 4 waves; each wave owns ONE 16-row subtile of Wh.
// grid = 512 graphs * 4 quarters. Writes:
//   whG  : bf16 Wh in GEMM-2 fragment-chunk layout (32 KB/graph),
//          q-slot swizzled by (m&3)^((m>>2)&3) so kernel B's LDS reads are 2-way
//   wh1G/wh2G : fp32, pre-scaled by LOG2E
__global__ __launch_bounds__(256, 4)
void gat_wh(const float* __restrict__ h, const float* __restrict__ W,
            const float* __restrict__ a,
            unsigned short* __restrict__ whG,
            float* __restrict__ wh1G, float* __restrict__ wh2G)
{
  const int bid  = blockIdx.x;
  const int g    = bid >> 2;          // graph (b*t)
  const int qt   = bid & 3;           // quarter: rows 64*qt..+63
  const int tid  = threadIdx.x;
  const int lane = tid & 63;
  const int w2   = tid >> 6;          // wave 0..3
  const int m    = lane & 15;
  const int q    = lane >> 4;
  const int R    = 64 * qt + 16 * w2; // wave's 16-row base (16-aligned)

  __shared__ __align__(16) unsigned short sWT[64 * 136]; // bf16 W^T [o][k], padded

  const float* __restrict__ hB = h + (size_t)g * NN * FI;

  // 16 rows of h: lane (m,q) -> row R+m, cols kt*32 + q*8 (+0,+4). Issued up front.
  float4 x[4][2];
  #pragma unroll
  for (int kt = 0; kt < 4; ++kt) {
    const float* p = hB + (size_t)(R + m) * FI + kt * 32 + q * 8;
    x[kt][0] = *(const float4*)p;
    x[kt][1] = *(const float4*)(p + 4);
  }

  // Stage W (fp32 [k][o], 32 KB, L2-hot) -> sWT bf16 [o][k].
  // k-paired: read rows k,k+1 same o-quad, pack along k -> 16 ds_write_b32
  // per thread. 4 iters x 256 thr x (2k x 4o) = 8192.
  #pragma unroll
  for (int it = 0; it < 4; ++it) {
    int idx = it * 256 + tid;          // 0..1023
    int k   = (idx >> 4) << 1;         // even k: 0,2,..,126
    int o   = (idx & 15) << 2;         // 0,4,..,60
    float4 wa = *(const float4*)&W[k * FO + o];
    float4 wb = *(const float4*)&W[(k + 1) * FO + o];
    *(unsigned*)&sWT[(o + 0) * 136 + k] = pack2(wa.x, wb.x);
    *(unsigned*)&sWT[(o + 1) * 136 + k] = pack2(wa.y, wb.y);
    *(unsigned*)&sWT[(o + 2) * 136 + k] = pack2(wa.z, wb.z);
    *(unsigned*)&sWT[(o + 3) * 136 + k] = pack2(wa.w, wb.w);
  }

  // a-vector values (512 B, L1-broadcast)
  float a1v[4], a2v[4];
  #pragma unroll
  for (int nt = 0; nt < 4; ++nt) {
    a1v[nt] = a[16 * nt + m];
    a2v[nt] = a[FO + 16 * nt + m];
  }

  s16x8 af[4];
  #pragma unroll
  for (int kt = 0; kt < 4; ++kt) {
    union { unsigned u[4]; s16x8 v; } pk;
    pk.u[0] = pack2(x[kt][0].x, x[kt][0].y);
    pk.u[1] = pack2(x[kt][0].z, x[kt][0].w);
    pk.u[2] = pack2(x[kt][1].x, x[kt][1].y);
    pk.u[3] = pack2(x[kt][1].z, x[kt][1].w);
    af[kt] = pk.v;
  }

  __syncthreads();   // sWT ready

  f32x4 acc[4];
  #pragma unroll
  for (int nt = 0; nt < 4; ++nt) acc[nt] = (f32x4){0.f, 0.f, 0.f, 0.f};
  #pragma unroll
  for (int kt = 0; kt < 4; ++kt)
    #pragma unroll
    for (int nt = 0; nt < 4; ++nt) {
      s16x8 bf = *(const s16x8*)&sWT[(16 * nt + m) * 136 + kt * 32 + q * 8];
      acc[nt] = __builtin_amdgcn_mfma_f32_16x16x32_bf16(af[kt], bf, acc[nt], 0, 0, 0);
    }

  // wh1/wh2 epilogue (acc[nt][r] = Wh[R+4q+r][16nt+m]); store x log2e
  {
    float p1[4] = {0.f,0.f,0.f,0.f}, p2[4] = {0.f,0.f,0.f,0.f};
    #pragma unroll
    for (int nt = 0; nt < 4; ++nt) {
      #pragma unroll
      for (int r = 0; r < 4; ++r) { p1[r] += acc[nt][r] * a1v[nt]; p2[r] += acc[nt][r] * a2v[nt]; }
    }
    #pragma unroll
    for (int off = 1; off < 16; off <<= 1)
      #pragma unroll
      for (int r = 0; r < 4; ++r) {
        p1[r] += __shfl_xor(p1[r], off);
        p2[r] += __shfl_xor(p2[r], off);
      }
    if (m == 0) {
      *(float4*)&wh1G[g * NN + R + 4 * q] =
          make_float4(p1[0]*LOG2E, p1[1]*LOG2E, p1[2]*LOG2E, p1[3]*LOG2E);
      *(float4*)&wh2G[g * NN + R + 4 * q] =
          make_float4(p2[0]*LOG2E, p2[1]*LOG2E, p2[2]*LOG2E, p2[3]*LOG2E);
    }
  }

  // Wh -> global frag-chunk layout, q-slot PRE-SWIZZLED for kernel B's LDS
  // bank pattern (rule #21: swizzled source + linear LDS copy + swizzled read).
  // chunk = ((Wv*4+nt)*16+m)*4 + (qB ^ (m&3) ^ ((m>>2)&3)), 16B chunks.
  {
    const int Wv  = R >> 5;          // 0..7 (matches GEMM-2's kt)
    const int S   = (R >> 4) & 1;
    const int qB  = (2 * S + (q >> 1)) & 3;
    const int swz = (m & 3) ^ ((m >> 2) & 3);
    unsigned short* whP = whG + (size_t)g * (NN * FO);
    #pragma unroll
    for (int nt = 0; nt < 4; ++nt) {
      int chunk = ((Wv * 4 + nt) * 16 + m) * 4 + (qB ^ swz);
      uint2 wrv;
      wrv.x = pack2(acc[nt][0], acc[nt][1]);
      wrv.y = pack2(acc[nt][2], acc[nt][3]);
      *(uint2*)((char*)whP + chunk * 16 + (q & 1) * 8) = wrv;
    }
  }
}

// ---------------- Kernel B: softmax + GEMM-2 + elu.
// 512 threads = 8 waves, 16 rows/wave, HALF a graph per block; grid = 1024
// (round-8 structure: 4 blocks/CU queued). Staging via global_load_lds (zero
// regs, drained by the one __syncthreads). Masking via 256-bit row bitmasks
// (8 KB L1-resident) instead of divergent adj float4 loads (round-9 fix).
// waves_per_eu(4,4): pins allocator target at exactly 4 waves/EU -> VGPR
// budget 128 with NO incentive to squeeze lower. Round-9 lesson: the (4,8)
// RANGE let the allocator target 8 waves/EU -> 64 VGPR -> ~72 MB scratch
// spill (WRITE_SIZE 105 MB vs 33 expected) -> 52 us. Never give the
// allocator a max above what the block layout needs.
__global__ __launch_bounds__(512)
__attribute__((amdgpu_waves_per_eu(4, 4)))
void gat_attn(const unsigned short* __restrict__ whG,
              const float* __restrict__ wh1G, const float* __restrict__ wh2G,
              const unsigned* __restrict__ msk, float* __restrict__ out)
{
  const int bid  = blockIdx.x;
  const int g    = bid >> 1;
  const int hf   = bid & 1;                 // which 128 rows this block owns
  const int tid  = threadIdx.x;
  const int lane = tid & 63;
  const int w2   = tid >> 6;                // wave 0..7
  const int m    = lane & 15;
  const int q    = lane >> 4;
  const int row  = 128 * hf + 16 * w2 + m;  // this lane's attention row

  __shared__ __align__(16) unsigned short sWh[NN * FO]; // 32 KB staged Wh

  const unsigned short* __restrict__ whP = whG + (size_t)g * (NN * FO);
  const float* __restrict__ wh2B = wh2G + g * NN;

  // ---- stage: async copy of the graph's 32 KB whG into LDS (linear copy;
  // swizzle pre-baked in whG's global layout). 4 x 16B per thread, coalesced,
  // zero registers held; drained by the __syncthreads below.
  #pragma unroll
  for (int i = 0; i < 4; ++i) {
    int c = i * 512 + tid;
    gload_lds16(whP + (size_t)c * 8, &sWh[(size_t)c * 8]);
  }

  // row bitmask: 2 x uint4 (32B) per row, L1-hot table
  const uint4 mka = *(const uint4*)&msk[row * 8];
  const uint4 mkb = *(const uint4*)&msk[row * 8 + 4];
  const unsigned mkw[8] = {mka.x, mka.y, mka.z, mka.w, mkb.x, mkb.y, mkb.z, mkb.w};
  const float w1 = wh1G[g * NN + row];      // pre-scaled by log2e

  // ---- softmax: pure ALU + wave-uniform wh2 loads (1 KB/graph, L1-hot)
  s16x8 A[8];                               // alpha, B-fragment layout
  float sum = 0.f;
  #pragma unroll
  for (int kt = 0; kt < 8; ++kt) {
    int j0 = kt * 32 + q * 8;
    float4 w20 = *(const float4*)&wh2B[j0];
    float4 w21 = *(const float4*)&wh2B[j0 + 4];
    unsigned wq = mkw[kt] >> (q * 8);
    float p[8];
    const float w2e[8] = {w20.x, w20.y, w20.z, w20.w, w21.x, w21.y, w21.z, w21.w};
    #pragma unroll
    for (int e = 0; e < 8; ++e) {
      float l = w1 + w2e[e];
      l = fmaxf(l, 0.01f * l);                 // leaky-relu (log2e pre-folded)
      union { float f; int i; } u_; u_.f = fexp2(l);
      u_.i &= ((int)(wq << (31 - e))) >> 31;   // adj bit -> 0 / all-ones
      p[e] = u_.f;
      sum += u_.f;
    }
    union { unsigned u[4]; s16x8 v; } pk;
    pk.u[0] = pktrunc(p[0], p[1]);
    pk.u[1] = pktrunc(p[2], p[3]);
    pk.u[2] = pktrunc(p[4], p[5]);
    pk.u[3] = pktrunc(p[6], p[7]);
    A[kt] = pk.v;
  }
  sum += __shfl_xor(sum, 16);
  sum += __shfl_xor(sum, 32);
  const float inv = __builtin_amdgcn_rcpf(sum);

  __syncthreads();   // drains vmcnt: staging landed; sWh ready

  // ---- GEMM-2 swapped: D = Wh^T(A-op) @ alpha^T(B-op), fragments from LDS.
  // Read swizzle matches gat_wh's write swizzle -> each wave instruction
  // covers one contiguous 1 KB block (worst 2-way banks = free, m136).
  const int swz = (m & 3) ^ ((m >> 2) & 3);
  f32x4 acc[4];
  #pragma unroll
  for (int ot = 0; ot < 4; ++ot) acc[ot] = (f32x4){0.f, 0.f, 0.f, 0.f};
  #pragma unroll
  for (int kt = 0; kt < 8; ++kt) {
    #pragma unroll
    for (int ot = 0; ot < 4; ++ot) {
      int chunk = ((kt * 4 + ot) * 16 + m) * 4 + (q ^ swz);
      s16x8 whf = *(const s16x8*)&sWh[chunk * 8];
      acc[ot] = __builtin_amdgcn_mfma_f32_16x16x32_bf16(whf, A[kt], acc[ot], 0, 0, 0);
    }
  }

  // epilogue: lane(m,q) holds out[row][16ot+4q .. +3]
  float* outB = out + (size_t)g * NN * FO;
  #pragma unroll
  for (int ot = 0; ot < 4; ++ot) {
    float4 v4;
    float* vp = (float*)&v4;
    #pragma unroll
    for (int r = 0; r < 4; ++r) {
      float v = acc[ot][r] * inv;
      float ev = fexp2(v * LOG2E) - 1.f;
      vp[r] = v > 0.f ? v : ev;
    }
    *(float4*)&outB[row * FO + 16 * ot + 4 * q] = v4;
  }
}

extern "C" void kernel_launch(void* const* d_in, const int* in_sizes, int n_in,
                              void* d_out, int out_size, void* d_ws, size_t ws_size,
                              hipStream_t stream) {
  const float* h   = (const float*)d_in[0];
  const float* W   = (const float*)d_in[1];
  const float* a   = (const float*)d_in[2];
  const float* adj = (const float*)d_in[3];
  float* out = (float*)d_out;

  // workspace layout (all 16B-aligned):
  //   msk  : 8 KiB    (256-bit adjacency bitmask per row)
  //   wh1G : 512 KiB  (fp32, pre-scaled by log2e)
  //   wh2G : 512 KiB
  //   whG  : 16 MiB   (bf16 Wh, frag-chunk layout, 32 KB/graph)
  char* ws = (char*)d_ws;
  unsigned*        msk  = (unsigned*)(ws);
  float*           wh1G = (float*)(ws + 8192);
  float*           wh2G = (float*)(ws + 8192 + 524288);
  unsigned short*  whG  = (unsigned short*)(ws + 8192 + 2 * 524288);

  gat_k0  <<<dim3(256),  dim3(256), 0, stream>>>(adj, msk);
  gat_wh  <<<dim3(2048), dim3(256), 0, stream>>>(h, W, a, whG, wh1G, wh2G);
  gat_attn<<<dim3(1024), dim3(512), 0, stream>>>(whG, wh1G, wh2G, msk, out);
}

// Round 11
// 127.704 us; speedup vs baseline: 1.2525x; 1.0181x over previous
//
#include <hip/hip_runtime.h>
#include <hip/hip_bf16.h>

#define NN 256
#define FI 128
#define FO 64
#define LOG2E 1.4426950408889634f

typedef short s16x8 __attribute__((ext_vector_type(8)));
typedef float f32x4 __attribute__((ext_vector_type(4)));

__device__ __forceinline__ unsigned f2bf1(float x) {
  union { float f; unsigned u; } v; v.f = x;
  unsigned r = v.u + 0x7FFFu + ((v.u >> 16) & 1u);
  return r >> 16;
}
__device__ __forceinline__ unsigned pack2(float a, float b) {
  return f2bf1(a) | (f2bf1(b) << 16);
}
// one-instruction bf16x2 pack (truncation) via v_perm_b32 — alpha only
__device__ __forceinline__ unsigned pktrunc(float lo, float hi) {
  union { float f; unsigned u; } a, b; a.f = hi; b.f = lo;
  return __builtin_amdgcn_perm(a.u, b.u, 0x07060302u);
}
__device__ __forceinline__ float fexp2(float x) {
#if __has_builtin(__builtin_amdgcn_exp2f)
  return __builtin_amdgcn_exp2f(x);
#else
  return exp2f(x);
#endif
}

// async global->LDS, 16B per lane, zero VGPR round-trip (vmcnt-tracked;
// __syncthreads drains it). LDS dest = wave-uniform base + lane*16 (m104).
__device__ __forceinline__ void gload_lds16(const void* g, void* l) {
#if __has_builtin(__builtin_amdgcn_global_load_lds)
  __builtin_amdgcn_global_load_lds(
      (const __attribute__((address_space(1))) unsigned*)g,
      (__attribute__((address_space(3))) unsigned*)l, 16, 0, 0);
#else
  *(uint4*)l = *(const uint4*)g;   // fallback (sync copy)
#endif
}

// ---------------- Kernel A: GEMM-1 (+ fused adj->bitmask for bid<256).
// 256 threads = 4 waves; each wave owns ONE 16-row subtile of Wh.
// grid = 512 graphs * 4 quarters. Writes:
//   whG  : bf16 Wh in GEMM-2 fragment-chunk layout (32 KB/graph),
//          q-slot swizzled by (m&3)^((m>>2)&3) so kernel B's LDS reads are 2-way
//   wh1G/wh2G : fp32, pre-scaled by LOG2E
//   msk  : 256-bit adjacency bitmask per row (blocks 0..255 only; ~1 KB read
//          + ballot each -- replaces the former gat_k0 launch + gap)
__global__ __launch_bounds__(256, 4)
void gat_wh(const float* __restrict__ h, const float* __restrict__ W,
            const float* __restrict__ a, const float* __restrict__ adj,
            unsigned short* __restrict__ whG,
            float* __restrict__ wh1G, float* __restrict__ wh2G,
            unsigned* __restrict__ msk)
{
  const int bid  = blockIdx.x;
  const int g    = bid >> 2;          // graph (b*t)
  const int qt   = bid & 3;           // quarter: rows 64*qt..+63
  const int tid  = threadIdx.x;
  const int lane = tid & 63;
  const int w2   = tid >> 6;          // wave 0..3
  const int m    = lane & 15;
  const int q    = lane >> 4;
  const int R    = 64 * qt + 16 * w2; // wave's 16-row base (16-aligned)

  __shared__ __align__(16) unsigned short sWT[64 * 136]; // bf16 W^T [o][k], padded

  const float* __restrict__ hB = h + (size_t)g * NN * FI;

  // 16 rows of h: lane (m,q) -> row R+m, cols kt*32 + q*8 (+0,+4). Issued up front.
  float4 x[4][2];
  #pragma unroll
  for (int kt = 0; kt < 4; ++kt) {
    const float* p = hB + (size_t)(R + m) * FI + kt * 32 + q * 8;
    x[kt][0] = *(const float4*)p;
    x[kt][1] = *(const float4*)(p + 4);
  }

  // fused k0: first 256 blocks each compute one mask row (wave-uniform branch)
  if (bid < NN) {
    float v = adj[bid * NN + w2 * 64 + lane];
    unsigned long long b = __ballot(v > 0.f);
    if (lane == 0) {
      msk[bid * 8 + w2 * 2]     = (unsigned)b;
      msk[bid * 8 + w2 * 2 + 1] = (unsigned)(b >> 32);
    }
  }

  // Stage W (fp32 [k][o], 32 KB, L2-hot) -> sWT bf16 [o][k].
  // k-paired: read rows k,k+1 same o-quad, pack along k -> 16 ds_write_b32
  // per thread. 4 iters x 256 thr x (2k x 4o) = 8192.
  #pragma unroll
  for (int it = 0; it < 4; ++it) {
    int idx = it * 256 + tid;          // 0..1023
    int k   = (idx >> 4) << 1;         // even k: 0,2,..,126
    int o   = (idx & 15) << 2;         // 0,4,..,60
    float4 wa = *(const float4*)&W[k * FO + o];
    float4 wb = *(const float4*)&W[(k + 1) * FO + o];
    *(unsigned*)&sWT[(o + 0) * 136 + k] = pack2(wa.x, wb.x);
    *(unsigned*)&sWT[(o + 1) * 136 + k] = pack2(wa.y, wb.y);
    *(unsigned*)&sWT[(o + 2) * 136 + k] = pack2(wa.z, wb.z);
    *(unsigned*)&sWT[(o + 3) * 136 + k] = pack2(wa.w, wb.w);
  }

  // a-vector values (512 B, L1-broadcast)
  float a1v[4], a2v[4];
  #pragma unroll
  for (int nt = 0; nt < 4; ++nt) {
    a1v[nt] = a[16 * nt + m];
    a2v[nt] = a[FO + 16 * nt + m];
  }

  s16x8 af[4];
  #pragma unroll
  for (int kt = 0; kt < 4; ++kt) {
    union { unsigned u[4]; s16x8 v; } pk;
    pk.u[0] = pack2(x[kt][0].x, x[kt][0].y);
    pk.u[1] = pack2(x[kt][0].z, x[kt][0].w);
    pk.u[2] = pack2(x[kt][1].x, x[kt][1].y);
    pk.u[3] = pack2(x[kt][1].z, x[kt][1].w);
    af[kt] = pk.v;
  }

  __syncthreads();   // sWT ready

  f32x4 acc[4];
  #pragma unroll
  for (int nt = 0; nt < 4; ++nt) acc[nt] = (f32x4){0.f, 0.f, 0.f, 0.f};
  #pragma unroll
  for (int kt = 0; kt < 4; ++kt)
    #pragma unroll
    for (int nt = 0; nt < 4; ++nt) {
      s16x8 bf = *(const s16x8*)&sWT[(16 * nt + m) * 136 + kt * 32 + q * 8];
      acc[nt] = __builtin_amdgcn_mfma_f32_16x16x32_bf16(af[kt], bf, acc[nt], 0, 0, 0);
    }

  // wh1/wh2 epilogue (acc[nt][r] = Wh[R+4q+r][16nt+m]); store x log2e
  {
    float p1[4] = {0.f,0.f,0.f,0.f}, p2[4] = {0.f,0.f,0.f,0.f};
    #pragma unroll
    for (int nt = 0; nt < 4; ++nt) {
      #pragma unroll
      for (int r = 0; r < 4; ++r) { p1[r] += acc[nt][r] * a1v[nt]; p2[r] += acc[nt][r] * a2v[nt]; }
    }
    #pragma unroll
    for (int off = 1; off < 16; off <<= 1)
      #pragma unroll
      for (int r = 0; r < 4; ++r) {
        p1[r] += __shfl_xor(p1[r], off);
        p2[r] += __shfl_xor(p2[r], off);
      }
    if (m == 0) {
      *(float4*)&wh1G[g * NN + R + 4 * q] =
          make_float4(p1[0]*LOG2E, p1[1]*LOG2E, p1[2]*LOG2E, p1[3]*LOG2E);
      *(float4*)&wh2G[g * NN + R + 4 * q] =
          make_float4(p2[0]*LOG2E, p2[1]*LOG2E, p2[2]*LOG2E, p2[3]*LOG2E);
    }
  }

  // Wh -> global frag-chunk layout, q-slot PRE-SWIZZLED for kernel B's LDS
  // bank pattern (rule #21: swizzled source + linear LDS copy + swizzled read).
  // chunk = ((Wv*4+nt)*16+m)*4 + (qB ^ (m&3) ^ ((m>>2)&3)), 16B chunks.
  {
    const int Wv  = R >> 5;          // 0..7 (matches GEMM-2's kt)
    const int S   = (R >> 4) & 1;
    const int qB  = (2 * S + (q >> 1)) & 3;
    const int swz = (m & 3) ^ ((m >> 2) & 3);
    unsigned short* whP = whG + (size_t)g * (NN * FO);
    #pragma unroll
    for (int nt = 0; nt < 4; ++nt) {
      int chunk = ((Wv * 4 + nt) * 16 + m) * 4 + (qB ^ swz);
      uint2 wrv;
      wrv.x = pack2(acc[nt][0], acc[nt][1]);
      wrv.y = pack2(acc[nt][2], acc[nt][3]);
      *(uint2*)((char*)whP + chunk * 16 + (q & 1) * 8) = wrv;
    }
  }
}

// ---------------- Kernel B: softmax + GEMM-2 + elu.
// 512 threads = 8 waves, 16 rows/wave, HALF a graph per block; grid = 1024.
// Staging via global_load_lds (zero regs, drained by the one __syncthreads).
// Masking via 256-bit row bitmasks (8 KB L1-resident).
// waves_per_eu(6,6): pins allocator at exactly 6 waves/EU -> VGPR budget ~84
// -> 3 resident blocks/CU (LDS 96 of 160 KB), +50% TLP vs round-10's (4,4).
// Evidence this fits: round 2's phase-B (superset state: A[8]+acc+mkw plus
// phase-A leftovers) compiled to exactly 80 VGPR, zero scratch. Round-9
// lesson stands: the budget is pinned EXACTLY (min==max), never a range.
__global__ __launch_bounds__(512)
__attribute__((amdgpu_waves_per_eu(6, 6)))
void gat_attn(const unsigned short* __restrict__ whG,
              const float* __restrict__ wh1G, const float* __restrict__ wh2G,
              const unsigned* __restrict__ msk, float* __restrict__ out)
{
  const int bid  = blockIdx.x;
  const int g    = bid >> 1;
  const int hf   = bid & 1;                 // which 128 rows this block owns
  const int tid  = threadIdx.x;
  const int lane = tid & 63;
  const int w2   = tid >> 6;                // wave 0..7
  const int m    = lane & 15;
  const int q    = lane >> 4;
  const int row  = 128 * hf + 16 * w2 + m;  // this lane's attention row

  __shared__ __align__(16) unsigned short sWh[NN * FO]; // 32 KB staged Wh

  const unsigned short* __restrict__ whP = whG + (size_t)g * (NN * FO);
  const float* __restrict__ wh2B = wh2G + g * NN;

  // ---- stage: async copy of the graph's 32 KB whG into LDS (linear copy;
  // swizzle pre-baked in whG's global layout). 4 x 16B per thread, coalesced,
  // zero registers held; drained by the __syncthreads below.
  #pragma unroll
  for (int i = 0; i < 4; ++i) {
    int c = i * 512 + tid;
    gload_lds16(whP + (size_t)c * 8, &sWh[(size_t)c * 8]);
  }

  // row bitmask: 2 x uint4 (32B) per row, L1-hot table
  const uint4 mka = *(const uint4*)&msk[row * 8];
  const uint4 mkb = *(const uint4*)&msk[row * 8 + 4];
  const unsigned mkw[8] = {mka.x, mka.y, mka.z, mka.w, mkb.x, mkb.y, mkb.z, mkb.w};
  const float w1 = wh1G[g * NN + row];      // pre-scaled by log2e

  // ---- softmax: pure ALU + wave-uniform wh2 loads (1 KB/graph, L1-hot)
  s16x8 A[8];                               // alpha, B-fragment layout
  float sum = 0.f;
  #pragma unroll
  for (int kt = 0; kt < 8; ++kt) {
    int j0 = kt * 32 + q * 8;
    float4 w20 = *(const float4*)&wh2B[j0];
    float4 w21 = *(const float4*)&wh2B[j0 + 4];
    unsigned wq = mkw[kt] >> (q * 8);
    float p[8];
    const float w2e[8] = {w20.x, w20.y, w20.z, w20.w, w21.x, w21.y, w21.z, w21.w};
    #pragma unroll
    for (int e = 0; e < 8; ++e) {
      float l = w1 + w2e[e];
      l = fmaxf(l, 0.01f * l);                 // leaky-relu (log2e pre-folded)
      union { float f; int i; } u_; u_.f = fexp2(l);
      u_.i &= ((int)(wq << (31 - e))) >> 31;   // adj bit -> 0 / all-ones
      p[e] = u_.f;
      sum += u_.f;
    }
    union { unsigned u[4]; s16x8 v; } pk;
    pk.u[0] = pktrunc(p[0], p[1]);
    pk.u[1] = pktrunc(p[2], p[3]);
    pk.u[2] = pktrunc(p[4], p[5]);
    pk.u[3] = pktrunc(p[6], p[7]);
    A[kt] = pk.v;
  }
  sum += __shfl_xor(sum, 16);
  sum += __shfl_xor(sum, 32);
  const float inv = __builtin_amdgcn_rcpf(sum);

  __syncthreads();   // drains vmcnt: staging landed; sWh ready

  // ---- GEMM-2 swapped: D = Wh^T(A-op) @ alpha^T(B-op), fragments from LDS.
  // Read swizzle matches gat_wh's write swizzle -> each wave instruction
  // covers one contiguous 1 KB block (worst 2-way banks = free, m136).
  const int swz = (m & 3) ^ ((m >> 2) & 3);
  f32x4 acc[4];
  #pragma unroll
  for (int ot = 0; ot < 4; ++ot) acc[ot] = (f32x4){0.f, 0.f, 0.f, 0.f};
  #pragma unroll
  for (int kt = 0; kt < 8; ++kt) {
    #pragma unroll
    for (int ot = 0; ot < 4; ++ot) {
      int chunk = ((kt * 4 + ot) * 16 + m) * 4 + (q ^ swz);
      s16x8 whf = *(const s16x8*)&sWh[chunk * 8];
      acc[ot] = __builtin_amdgcn_mfma_f32_16x16x32_bf16(whf, A[kt], acc[ot], 0, 0, 0);
    }
  }

  // epilogue: lane(m,q) holds out[row][16ot+4q .. +3]
  float* outB = out + (size_t)g * NN * FO;
  #pragma unroll
  for (int ot = 0; ot < 4; ++ot) {
    float4 v4;
    float* vp = (float*)&v4;
    #pragma unroll
    for (int r = 0; r < 4; ++r) {
      float v = acc[ot][r] * inv;
      float ev = fexp2(v * LOG2E) - 1.f;
      vp[r] = v > 0.f ? v : ev;
    }
    *(float4*)&outB[row * FO + 16 * ot + 4 * q] = v4;
  }
}

extern "C" void kernel_launch(void* const* d_in, const int* in_sizes, int n_in,
                              void* d_out, int out_size, void* d_ws, size_t ws_size,
                              hipStream_t stream) {
  const float* h   = (const float*)d_in[0];
  const float* W   = (const float*)d_in[1];
  const float* a   = (const float*)d_in[2];
  const float* adj = (const float*)d_in[3];
  float* out = (float*)d_out;

  // workspace layout (all 16B-aligned):
  //   msk  : 8 KiB    (256-bit adjacency bitmask per row)
  //   wh1G : 512 KiB  (fp32, pre-scaled by log2e)
  //   wh2G : 512 KiB
  //   whG  : 16 MiB   (bf16 Wh, frag-chunk layout, 32 KB/graph)
  char* ws = (char*)d_ws;
  unsigned*        msk  = (unsigned*)(ws);
  float*           wh1G = (float*)(ws + 8192);
  float*           wh2G = (float*)(ws + 8192 + 524288);
  unsigned short*  whG  = (unsigned short*)(ws + 8192 + 2 * 524288);

  gat_wh  <<<dim3(2048), dim3(256), 0, stream>>>(h, W, a, adj, whG, wh1G, wh2G, msk);
  gat_attn<<<dim3(1024), dim3(512), 0, stream>>>(whG, wh1G, wh2G, msk, out);
}

// Round 13
// 126.276 us; speedup vs baseline: 1.2666x; 1.0113x over previous
//
#include <hip/hip_runtime.h>
#include <hip/hip_bf16.h>

#define NN 256
#define FI 128
#define FO 64
#define LOG2E 1.4426950408889634f

typedef short s16x8 __attribute__((ext_vector_type(8)));
typedef float f32x4 __attribute__((ext_vector_type(4)));

__device__ __forceinline__ unsigned f2bf1(float x) {
  union { float f; unsigned u; } v; v.f = x;
  unsigned r = v.u + 0x7FFFu + ((v.u >> 16) & 1u);
  return r >> 16;
}
__device__ __forceinline__ unsigned pack2(float a, float b) {
  return f2bf1(a) | (f2bf1(b) << 16);
}
// one-instruction bf16x2 pack (truncation) via v_perm_b32 — alpha only
__device__ __forceinline__ unsigned pktrunc(float lo, float hi) {
  union { float f; unsigned u; } a, b; a.f = hi; b.f = lo;
  return __builtin_amdgcn_perm(a.u, b.u, 0x07060302u);
}
__device__ __forceinline__ float fexp2(float x) {
#if __has_builtin(__builtin_amdgcn_exp2f)
  return __builtin_amdgcn_exp2f(x);
#else
  return exp2f(x);
#endif
}

// async global->LDS, 16B per lane, zero VGPR round-trip (vmcnt-tracked;
// __syncthreads drains it). LDS dest = wave-uniform base + lane*16 (m104).
__device__ __forceinline__ void gload_lds16(const void* g, void* l) {
#if __has_builtin(__builtin_amdgcn_global_load_lds)
  __builtin_amdgcn_global_load_lds(
      (const __attribute__((address_space(1))) unsigned*)g,
      (__attribute__((address_space(3))) unsigned*)l, 16, 0, 0);
#else
  *(uint4*)l = *(const uint4*)g;   // fallback (sync copy)
#endif
}

// ---------------- Kernel A: GEMM-1 (+ fused adj->bitmask for bid<256).
// 256 threads = 4 waves; each wave owns ONE 16-row subtile of Wh.
// grid = 512 graphs * 4 quarters. Writes:
//   whG  : bf16 Wh in GEMM-2 fragment-chunk layout (32 KB/graph),
//          q-slot swizzled by (m&3)^((m>>2)&3) so kernel B's LDS reads are 2-way
//   wh1G/wh2G : fp32, pre-scaled by LOG2E
//   msk  : 256-bit adjacency bitmask per row (blocks 0..255 only)
__global__ __launch_bounds__(256, 4)
void gat_wh(const float* __restrict__ h, const float* __restrict__ W,
            const float* __restrict__ a, const float* __restrict__ adj,
            unsigned short* __restrict__ whG,
            float* __restrict__ wh1G, float* __restrict__ wh2G,
            unsigned* __restrict__ msk)
{
  const int bid  = blockIdx.x;
  const int g    = bid >> 2;          // graph (b*t)
  const int qt   = bid & 3;           // quarter: rows 64*qt..+63
  const int tid  = threadIdx.x;
  const int lane = tid & 63;
  const int w2   = tid >> 6;          // wave 0..3
  const int m    = lane & 15;
  const int q    = lane >> 4;
  const int R    = 64 * qt + 16 * w2; // wave's 16-row base (16-aligned)

  __shared__ __align__(16) unsigned short sWT[64 * 136]; // bf16 W^T [o][k], padded

  const float* __restrict__ hB = h + (size_t)g * NN * FI;

  // 16 rows of h: lane (m,q) -> row R+m, cols kt*32 + q*8 (+0,+4). Issued up front.
  float4 x[4][2];
  #pragma unroll
  for (int kt = 0; kt < 4; ++kt) {
    const float* p = hB + (size_t)(R + m) * FI + kt * 32 + q * 8;
    x[kt][0] = *(const float4*)p;
    x[kt][1] = *(const float4*)(p + 4);
  }

  // fused k0: first 256 blocks each compute one mask row (wave-uniform branch)
  if (bid < NN) {
    float v = adj[bid * NN + w2 * 64 + lane];
    unsigned long long b = __ballot(v > 0.f);
    if (lane == 0) {
      msk[bid * 8 + w2 * 2]     = (unsigned)b;
      msk[bid * 8 + w2 * 2 + 1] = (unsigned)(b >> 32);
    }
  }

  // Stage W (fp32 [k][o], 32 KB, L2-hot) -> sWT bf16 [o][k].
  // k-paired: read rows k,k+1 same o-quad, pack along k -> 16 ds_write_b32
  // per thread. 4 iters x 256 thr x (2k x 4o) = 8192.
  #pragma unroll
  for (int it = 0; it < 4; ++it) {
    int idx = it * 256 + tid;          // 0..1023
    int k   = (idx >> 4) << 1;         // even k: 0,2,..,126
    int o   = (idx & 15) << 2;         // 0,4,..,60
    float4 wa = *(const float4*)&W[k * FO + o];
    float4 wb = *(const float4*)&W[(k + 1) * FO + o];
    *(unsigned*)&sWT[(o + 0) * 136 + k] = pack2(wa.x, wb.x);
    *(unsigned*)&sWT[(o + 1) * 136 + k] = pack2(wa.y, wb.y);
    *(unsigned*)&sWT[(o + 2) * 136 + k] = pack2(wa.z, wb.z);
    *(unsigned*)&sWT[(o + 3) * 136 + k] = pack2(wa.w, wb.w);
  }

  // a-vector values (512 B, L1-broadcast)
  float a1v[4], a2v[4];
  #pragma unroll
  for (int nt = 0; nt < 4; ++nt) {
    a1v[nt] = a[16 * nt + m];
    a2v[nt] = a[FO + 16 * nt + m];
  }

  s16x8 af[4];
  #pragma unroll
  for (int kt = 0; kt < 4; ++kt) {
    union { unsigned u[4]; s16x8 v; } pk;
    pk.u[0] = pack2(x[kt][0].x, x[kt][0].y);
    pk.u[1] = pack2(x[kt][0].z, x[kt][0].w);
    pk.u[2] = pack2(x[kt][1].x, x[kt][1].y);
    pk.u[3] = pack2(x[kt][1].z, x[kt][1].w);
    af[kt] = pk.v;
  }

  __syncthreads();   // sWT ready

  f32x4 acc[4];
  #pragma unroll
  for (int nt = 0; nt < 4; ++nt) acc[nt] = (f32x4){0.f, 0.f, 0.f, 0.f};
  #pragma unroll
  for (int kt = 0; kt < 4; ++kt)
    #pragma unroll
    for (int nt = 0; nt < 4; ++nt) {
      s16x8 bf = *(const s16x8*)&sWT[(16 * nt + m) * 136 + kt * 32 + q * 8];
      acc[nt] = __builtin_amdgcn_mfma_f32_16x16x32_bf16(af[kt], bf, acc[nt], 0, 0, 0);
    }

  // wh1/wh2 epilogue (acc[nt][r] = Wh[R+4q+r][16nt+m]); store x log2e
  {
    float p1[4] = {0.f,0.f,0.f,0.f}, p2[4] = {0.f,0.f,0.f,0.f};
    #pragma unroll
    for (int nt = 0; nt < 4; ++nt) {
      #pragma unroll
      for (int r = 0; r < 4; ++r) { p1[r] += acc[nt][r] * a1v[nt]; p2[r] += acc[nt][r] * a2v[nt]; }
    }
    #pragma unroll
    for (int off = 1; off < 16; off <<= 1)
      #pragma unroll
      for (int r = 0; r < 4; ++r) {
        p1[r] += __shfl_xor(p1[r], off);
        p2[r] += __shfl_xor(p2[r], off);
      }
    if (m == 0) {
      *(float4*)&wh1G[g * NN + R + 4 * q] =
          make_float4(p1[0]*LOG2E, p1[1]*LOG2E, p1[2]*LOG2E, p1[3]*LOG2E);
      *(float4*)&wh2G[g * NN + R + 4 * q] =
          make_float4(p2[0]*LOG2E, p2[1]*LOG2E, p2[2]*LOG2E, p2[3]*LOG2E);
    }
  }

  // Wh -> global frag-chunk layout, q-slot PRE-SWIZZLED for kernel B's LDS
  // bank pattern (rule #21: swizzled source + linear LDS copy + swizzled read).
  // chunk = ((Wv*4+nt)*16+m)*4 + (qB ^ (m&3) ^ ((m>>2)&3)), 16B chunks.
  {
    const int Wv  = R >> 5;          // 0..7 (matches GEMM-2's kt)
    const int S   = (R >> 4) & 1;
    const int qB  = (2 * S + (q >> 1)) & 3;
    const int swz = (m & 3) ^ ((m >> 2) & 3);
    unsigned short* whP = whG + (size_t)g * (NN * FO);
    #pragma unroll
    for (int nt = 0; nt < 4; ++nt) {
      int chunk = ((Wv * 4 + nt) * 16 + m) * 4 + (qB ^ swz);
      uint2 wrv;
      wrv.x = pack2(acc[nt][0], acc[nt][1]);
      wrv.y = pack2(acc[nt][2], acc[nt][3]);
      *(uint2*)((char*)whP + chunk * 16 + (q & 1) * 8) = wrv;
    }
  }
}

// ---------------- Kernel B: softmax + GEMM-2 + elu.
// 512 threads = 8 waves, 16 rows/wave, HALF a graph per block; grid = 1024.
// True staging/softmax overlap. vmcnt retires loads IN ISSUE ORDER (m135),
// so with staging issued first and softmax's wh2 VMEM loads after, the wait
// before the FIRST softmax use drained ALL staging loads: softmax never
// overlapped the HBM staging. Fix:
//   (a) msk/w1 per-lane loads issued FIRST (older than staging: waiting on
//       them never drains staging),
//   (b) wh2 (1 KB) cooperatively copied to LDS, __syncthreads (staging not
//       yet issued, so this drains only cheap L2 loads),
//   (c) issue the 4 gload_lds + sched_barrier(0) pin,
//   (d) softmax reads wh2 via ds_read -- lgkmcnt domain, independent of
//       vmcnt -> ZERO vmcnt waits inside softmax -> staging truly in flight
//       under ~1400 cyc of softmax ALU,
//   (e) __syncthreads drains staging, (f) MFMA.
// waves_per_eu(6,6) pinned exactly (round-9 lesson); LDS 33.8 KB -> 3
// blocks/CU; softmax live regs ~70 < 84 budget.
__global__ __launch_bounds__(512)
__attribute__((amdgpu_waves_per_eu(6, 6)))
void gat_attn(const unsigned short* __restrict__ whG,
              const float* __restrict__ wh1G, const float* __restrict__ wh2G,
              const unsigned* __restrict__ msk, float* __restrict__ out)
{
  const int bid  = blockIdx.x;
  const int g    = bid >> 1;
  const int hf   = bid & 1;                 // which 128 rows this block owns
  const int tid  = threadIdx.x;
  const int lane = tid & 63;
  const int w2   = tid >> 6;                // wave 0..7
  const int m    = lane & 15;
  const int q    = lane >> 4;
  const int row  = 128 * hf + 16 * w2 + m;  // this lane's attention row

  __shared__ __align__(16) unsigned short sWh[NN * FO]; // 32 KB staged Wh
  __shared__ __align__(16) float sW2[NN];               // 1 KB wh2 (softmax input)

  const unsigned short* __restrict__ whP = whG + (size_t)g * (NN * FO);
  const float* __restrict__ wh2B = wh2G + g * NN;

  // (a) per-lane loads, issued BEFORE staging (in-order vmcnt: waiting on
  // these never drains the staging loads). msk 8 KB + wh1 L1/L2-hot.
  const uint4 mka = *(const uint4*)&msk[row * 8];
  const uint4 mkb = *(const uint4*)&msk[row * 8 + 4];
  const float w1  = wh1G[g * NN + row];     // pre-scaled by log2e

  // (b) wh2 -> LDS (1 KB, 64 float4), then publish. Staging not yet issued,
  // so this barrier's vmcnt(0) drains only the cheap loads above.
  if (tid < 64) {
    float4 v = *(const float4*)&wh2B[tid * 4];
    *(float4*)&sW2[tid * 4] = v;
  }
  __syncthreads();

  // (c) stage: async copy of the graph's 32 KB whG into LDS (linear copy;
  // swizzle pre-baked in whG's global layout). 4 x 16B per thread, coalesced,
  // zero registers held; drained by the __syncthreads after softmax.
  #pragma unroll
  for (int i = 0; i < 4; ++i) {
    int c = i * 512 + tid;
    gload_lds16(whP + (size_t)c * 8, &sWh[(size_t)c * 8]);
  }
  __builtin_amdgcn_sched_barrier(0);   // pin: staging issued before softmax

  const unsigned mkw[8] = {mka.x, mka.y, mka.z, mka.w, mkb.x, mkb.y, mkb.z, mkb.w};

  // (d) softmax: wh2 from LDS (ds_read, lgkmcnt only -- no vmcnt waits),
  // mask from regs -> fully overlaps the staging HBM flight.
  s16x8 A[8];                               // alpha, B-fragment layout
  float sum = 0.f;
  #pragma unroll
  for (int kt = 0; kt < 8; ++kt) {
    int j0 = kt * 32 + q * 8;
    float4 w20 = *(const float4*)&sW2[j0];      // ds_read_b128, 4-addr broadcast
    float4 w21 = *(const float4*)&sW2[j0 + 4];
    unsigned wq = mkw[kt] >> (q * 8);
    float p[8];
    const float w2e[8] = {w20.x, w20.y, w20.z, w20.w, w21.x, w21.y, w21.z, w21.w};
    #pragma unroll
    for (int e = 0; e < 8; ++e) {
      float l = w1 + w2e[e];
      l = fmaxf(l, 0.01f * l);                 // leaky-relu (log2e pre-folded)
      union { float f; int i; } u_; u_.f = fexp2(l);
      u_.i &= ((int)(wq << (31 - e))) >> 31;   // adj bit -> 0 / all-ones
      p[e] = u_.f;
      sum += u_.f;
    }
    union { unsigned u[4]; s16x8 v; } pk;
    pk.u[0] = pktrunc(p[0], p[1]);
    pk.u[1] = pktrunc(p[2], p[3]);
    pk.u[2] = pktrunc(p[4], p[5]);
    pk.u[3] = pktrunc(p[6], p[7]);
    A[kt] = pk.v;
  }
  sum += __shfl_xor(sum, 16);
  sum += __shfl_xor(sum, 32);
  const float inv = __builtin_amdgcn_rcpf(sum);

  // (e) drains vmcnt: staging landed (overlapped with softmax); sWh ready
  __syncthreads();

  // (f) GEMM-2 swapped: D = Wh^T(A-op) @ alpha^T(B-op), fragments from LDS.
  // Read swizzle matches gat_wh's write swizzle -> each wave instruction
  // covers one contiguous 1 KB block (worst 2-way banks = free, m136).
  const int swz = (m & 3) ^ ((m >> 2) & 3);
  f32x4 acc[4];
  #pragma unroll
  for (int ot = 0; ot < 4; ++ot) acc[ot] = (f32x4){0.f, 0.f, 0.f, 0.f};
  #pragma unroll
  for (int kt = 0; kt < 8; ++kt) {
    #pragma unroll
    for (int ot = 0; ot < 4; ++ot) {
      int chunk = ((kt * 4 + ot) * 16 + m) * 4 + (q ^ swz);
      s16x8 whf = *(const s16x8*)&sWh[chunk * 8];
      acc[ot] = __builtin_amdgcn_mfma_f32_16x16x32_bf16(whf, A[kt], acc[ot], 0, 0, 0);
    }
  }

  // epilogue: lane(m,q) holds out[row][16ot+4q .. +3]
  float* outB = out + (size_t)g * NN * FO;
  #pragma unroll
  for (int ot = 0; ot < 4; ++ot) {
    float4 v4;
    float* vp = (float*)&v4;
    #pragma unroll
    for (int r = 0; r < 4; ++r) {
      float v = acc[ot][r] * inv;
      float ev = fexp2(v * LOG2E) - 1.f;
      vp[r] = v > 0.f ? v : ev;
    }
    *(float4*)&outB[row * FO + 16 * ot + 4 * q] = v4;
  }
}

extern "C" void kernel_launch(void* const* d_in, const int* in_sizes, int n_in,
                              void* d_out, int out_size, void* d_ws, size_t ws_size,
                              hipStream_t stream) {
  const float* h   = (const float*)d_in[0];
  const float* W   = (const float*)d_in[1];
  const float* a   = (const float*)d_in[2];
  const float* adj = (const float*)d_in[3];
  float* out = (float*)d_out;

  // workspace layout (all 16B-aligned):
  //   msk  : 8 KiB    (256-bit adjacency bitmask per row)
  //   wh1G : 512 KiB  (fp32, pre-scaled by log2e)
  //   wh2G : 512 KiB
  //   whG  : 16 MiB   (bf16 Wh, frag-chunk layout, 32 KB/graph)
  char* ws = (char*)d_ws;
  unsigned*        msk  = (unsigned*)(ws);
  float*           wh1G = (float*)(ws + 8192);
  float*           wh2G = (float*)(ws + 8192 + 524288);
  unsigned short*  whG  = (unsigned short*)(ws + 8192 + 2 * 524288);

  gat_wh  <<<dim3(2048), dim3(256), 0, stream>>>(h, W, a, adj, whG, wh1G, wh2G, msk);
  gat_attn<<<dim3(1024), dim3(512), 0, stream>>>(whG, wh1G, wh2G, msk, out);
}